// Round 1
// baseline (242.248 us; speedup 1.0000x reference)
//
#include <hip/hip_runtime.h>
#include <cstdint>
#include <cstddef>

// Problem constants
#define NIMG 32
#define C    128
#define OC   128
#define HW   112
#define HWSZ (HW * HW)      // 12544
#define PHW  114            // padded spatial dim
#define PIMG (PHW * PHW)    // 12996 padded cells per image
#define NTAP 9

// ---------------------------------------------------------------------------
// Zero-fill the padded packed-x buffer (borders must read as 0 bits).
__global__ void fill_zero_u4(uint4* __restrict__ p, int n) {
    int i = blockIdx.x * blockDim.x + threadIdx.x;
    if (i < n) p[i] = make_uint4(0u, 0u, 0u, 0u);
}

// ---------------------------------------------------------------------------
// Pack weights: (O=128, I=128, 3, 3) fp32 -> per (o,tap) 128-bit mask (uint4),
// bit c set iff w[o][c][tap] < 0.  Also store popcount per (o,tap) for the
// border correction.
__global__ void pack_weights(const float* __restrict__ w,
                             uint4* __restrict__ wpk,
                             int* __restrict__ popcw) {
    int idx = blockIdx.x * blockDim.x + threadIdx.x;   // (o, tap)
    if (idx >= OC * NTAP) return;
    int o = idx / NTAP, tap = idx % NTAP;
    uint32_t m[4] = {0u, 0u, 0u, 0u};
    for (int c = 0; c < C; ++c) {
        uint32_t bit = __float_as_uint(w[(size_t)(o * C + c) * NTAP + tap]) >> 31;
        m[c >> 5] |= bit << (c & 31);
    }
    wpk[idx] = make_uint4(m[0], m[1], m[2], m[3]);
    popcw[idx] = __popc(m[0]) + __popc(m[1]) + __popc(m[2]) + __popc(m[3]);
}

// ---------------------------------------------------------------------------
// Pack activations: x (N,C,112,112) fp32 -> padded bit buffer
// px[n][h+1][w+1] = uint4 of 128 channel sign bits.
// Each thread handles 4 consecutive w positions (float4 loads, coalesced).
__global__ void pack_x(const float* __restrict__ x, uint4* __restrict__ px) {
    int t = blockIdx.x * blockDim.x + threadIdx.x;
    const int per_img = HWSZ / 4;                      // 3136
    if (t >= NIMG * per_img) return;
    int n = t / per_img;
    int p = t % per_img;
    int hw0 = p * 4;
    int h = hw0 / HW, w0 = hw0 % HW;                   // 112 % 4 == 0: no row crossing

    uint32_t m[4][4] = {};
    const float* xp = x + (size_t)n * C * HWSZ + hw0;
    #pragma unroll 4
    for (int c = 0; c < C; ++c) {
        float4 v = *reinterpret_cast<const float4*>(xp + (size_t)c * HWSZ);
        uint32_t word = c >> 5, bit = c & 31;
        m[0][word] |= (__float_as_uint(v.x) >> 31) << bit;
        m[1][word] |= (__float_as_uint(v.y) >> 31) << bit;
        m[2][word] |= (__float_as_uint(v.z) >> 31) << bit;
        m[3][word] |= (__float_as_uint(v.w) >> 31) << bit;
    }
    uint4* dst = px + (size_t)n * PIMG + (size_t)(h + 1) * PHW + (w0 + 1);
    #pragma unroll
    for (int k = 0; k < 4; ++k)
        dst[k] = make_uint4(m[k][0], m[k][1], m[k][2], m[k][3]);
}

// ---------------------------------------------------------------------------
// Binary conv: out[n][o][h][w] = sum over 9 taps of (128 - 2*popc(X^W)),
// minus (128 - 2*popc(W_tap)) for taps that fall outside the image.
// Block = 256 threads = 256 consecutive hw positions of one image.
// blockIdx.y selects a 32-wide output-channel slab (better load balance).
__global__ __launch_bounds__(256) void bconv(const uint4* __restrict__ px,
                                             const uint4* __restrict__ wpk,
                                             const int* __restrict__ popcw,
                                             float* __restrict__ out) {
    int tile = blockIdx.x;                 // 0 .. 32*49-1
    int n = tile / 49;
    int hw = (tile % 49) * 256 + threadIdx.x;
    int h = hw / HW, w = hw % HW;

    const uint4* base = px + (size_t)n * PIMG + (size_t)h * PHW + w;
    uint4 xt[NTAP];
    #pragma unroll
    for (int kh = 0; kh < 3; ++kh)
        #pragma unroll
        for (int kw = 0; kw < 3; ++kw)
            xt[kh * 3 + kw] = base[kh * PHW + kw];

    // taps hanging off the image (their padded x bits are 0; correct later)
    int inv = 0;
    if (h == 0)      inv |= 0b000000111;
    if (h == HW - 1) inv |= 0b111000000;
    if (w == 0)      inv |= 0b001001001;
    if (w == HW - 1) inv |= 0b100100100;

    int o0 = blockIdx.y * 32;
    float* outp = out + (size_t)n * OC * HWSZ + hw;

    for (int o = o0; o < o0 + 32; ++o) {
        const uint4* wq = wpk + (size_t)o * NTAP;   // uniform -> scalar loads
        int a0 = 0, a1 = 0, a2 = 0, a3 = 0;
        #pragma unroll
        for (int t = 0; t < NTAP; ++t) {
            uint4 xv = xt[t];
            uint4 wv = wq[t];
            a0 += __popc(xv.x ^ wv.x);
            a1 += __popc(xv.y ^ wv.y);
            a2 += __popc(xv.z ^ wv.z);
            a3 += __popc(xv.w ^ wv.w);
        }
        int val = NTAP * C - 2 * (a0 + a1 + a2 + a3);
        if (inv) {
            #pragma unroll
            for (int t = 0; t < NTAP; ++t)
                if (inv & (1 << t)) val -= C - 2 * popcw[(size_t)o * NTAP + t];
        }
        outp[(size_t)o * HWSZ] = (float)val;
    }
}

// ---------------------------------------------------------------------------
extern "C" void kernel_launch(void* const* d_in, const int* in_sizes, int n_in,
                              void* d_out, int out_size, void* d_ws, size_t ws_size,
                              hipStream_t stream) {
    const float* x   = (const float*)d_in[0];
    const float* wts = (const float*)d_in[1];
    float* out = (float*)d_out;

    uint8_t* ws = (uint8_t*)d_ws;
    size_t px_bytes  = (size_t)NIMG * PIMG * sizeof(uint4);   // 6,653,952
    size_t wpk_bytes = (size_t)OC * NTAP * sizeof(uint4);     // 18,432
    uint4* px    = (uint4*)ws;
    uint4* wpk   = (uint4*)(ws + px_bytes);
    int*   popcw = (int*)(ws + px_bytes + wpk_bytes);

    int nfill = NIMG * PIMG;  // uint4 cells
    hipLaunchKernelGGL(fill_zero_u4, dim3((nfill + 255) / 256), dim3(256), 0, stream,
                       px, nfill);
    hipLaunchKernelGGL(pack_weights, dim3((OC * NTAP + 255) / 256), dim3(256), 0, stream,
                       wts, wpk, popcw);
    hipLaunchKernelGGL(pack_x, dim3((NIMG * (HWSZ / 4) + 255) / 256), dim3(256), 0, stream,
                       x, px);
    hipLaunchKernelGGL(bconv, dim3(NIMG * 49, 4), dim3(256), 0, stream,
                       px, wpk, popcw, out);
}

// Round 2
// 194.554 us; speedup vs baseline: 1.2451x; 1.2451x over previous
//
#include <hip/hip_runtime.h>
#include <cstdint>
#include <cstddef>

// Problem constants
#define NIMG 32
#define C    128
#define OC   128
#define HW   112
#define HWSZ (HW * HW)      // 12544
#define PHW  114            // padded spatial dim
#define PIMG (PHW * PHW)    // 12996 padded cells per image
#define NTAP 9

// ---------------------------------------------------------------------------
// Zero-fill the padded packed-x buffer (borders must read as 0 bits).
__global__ void fill_zero_u4(uint4* __restrict__ p, int n) {
    int i = blockIdx.x * blockDim.x + threadIdx.x;
    if (i < n) p[i] = make_uint4(0u, 0u, 0u, 0u);
}

// ---------------------------------------------------------------------------
// Pack weights: (O=128, I=128, 3, 3) fp32 -> per (o,tap) 128-bit mask (uint4),
// bit c set iff w[o][c][tap] < 0.  Also store popcount per (o,tap).
__global__ void pack_weights(const float* __restrict__ w,
                             uint4* __restrict__ wpk,
                             int* __restrict__ popcw) {
    int idx = blockIdx.x * blockDim.x + threadIdx.x;   // (o, tap)
    if (idx >= OC * NTAP) return;
    int o = idx / NTAP, tap = idx % NTAP;
    uint32_t m[4] = {0u, 0u, 0u, 0u};
    for (int c = 0; c < C; ++c) {
        uint32_t bit = __float_as_uint(w[(size_t)(o * C + c) * NTAP + tap]) >> 31;
        m[c >> 5] |= bit << (c & 31);
    }
    wpk[idx] = make_uint4(m[0], m[1], m[2], m[3]);
    popcw[idx] = __popc(m[0]) + __popc(m[1]) + __popc(m[2]) + __popc(m[3]);
}

// ---------------------------------------------------------------------------
// Border-correction table: corr[pat][o] = sum over invalid taps of
// (C - 2*popcw[o][tap]).  pat = pt*3+pw, pt: 0=interior 1=top(h==0)
// 2=bottom(h==111); pw: 0=interior 1=left(w==0) 2=right(w==111). pat 0 -> 0.
__global__ void mk_corr(const int* __restrict__ popcw, int* __restrict__ corr) {
    int idx = blockIdx.x * blockDim.x + threadIdx.x;   // pat*128 + o
    if (idx >= 9 * OC) return;
    int pat = idx >> 7, o = idx & 127;
    int pt = pat / 3, pw = pat % 3;
    int inv = 0;
    if (pt == 1) inv |= 0b000000111;
    if (pt == 2) inv |= 0b111000000;
    if (pw == 1) inv |= 0b001001001;
    if (pw == 2) inv |= 0b100100100;
    int s = 0;
    for (int t = 0; t < NTAP; ++t)
        if ((inv >> t) & 1) s += C - 2 * popcw[o * NTAP + t];
    corr[idx] = s;
}

// ---------------------------------------------------------------------------
// Pack activations: x (N,C,112,112) fp32 -> padded bit buffer.
// One thread = (n, word-of-32-channels, 4 consecutive w positions).
// 4x the parallelism of one-thread-per-pixel-group: 1568 blocks.
__global__ void pack_x(const float* __restrict__ x, uint32_t* __restrict__ pxw) {
    int t = blockIdx.x * blockDim.x + threadIdx.x;
    const int per_img = HWSZ / 4;                      // 3136 (divisible by 64)
    if (t >= NIMG * 4 * per_img) return;
    int p = t % per_img;                               // lane-fastest -> coalesced
    int g = t / per_img;
    int word = g & 3, n = g >> 2;
    int hw0 = p * 4;
    int h = hw0 / HW, w0 = hw0 % HW;                   // 112 % 4 == 0: no row crossing

    uint32_t m[4] = {0u, 0u, 0u, 0u};
    const float* xp = x + ((size_t)n * C + word * 32) * HWSZ + hw0;
    #pragma unroll
    for (int cc = 0; cc < 32; ++cc) {
        float4 v = *reinterpret_cast<const float4*>(xp + (size_t)cc * HWSZ);
        m[0] |= (__float_as_uint(v.x) >> 31) << cc;
        m[1] |= (__float_as_uint(v.y) >> 31) << cc;
        m[2] |= (__float_as_uint(v.z) >> 31) << cc;
        m[3] |= (__float_as_uint(v.w) >> 31) << cc;
    }
    uint32_t* dst = pxw + (((size_t)n * PIMG + (size_t)(h + 1) * PHW + (w0 + 1)) << 2) + word;
    dst[0]  = m[0];
    dst[4]  = m[1];
    dst[8]  = m[2];
    dst[12] = m[3];
}

// ---------------------------------------------------------------------------
__device__ __forceinline__ void bcnt_acc(uint32_t& acc, uint32_t v) {
    // acc = popc(v) + acc, guaranteed single instruction
    asm("v_bcnt_u32_b32 %0, %1, %0" : "+v"(acc) : "v"(v));
}

// Binary conv: out[n][o][h][w] = 9*128 - corr[pat] - 2*popc(X^W).
// Block = 256 consecutive hw positions of one image; blockIdx.y = 32-wide
// output-channel slab.  Border correction is a branch-free LDS table lookup.
__global__ __launch_bounds__(256) void bconv(const uint4* __restrict__ px,
                                             const uint4* __restrict__ wpk,
                                             const int* __restrict__ corr,
                                             float* __restrict__ out) {
    __shared__ int scorr[9 * OC];
    for (int i = threadIdx.x; i < 9 * OC; i += 256) scorr[i] = corr[i];
    __syncthreads();

    int tile = blockIdx.x;                 // 0 .. 32*49-1
    int n = tile / 49;
    int hw = (tile % 49) * 256 + threadIdx.x;
    int h = hw / HW, w = hw % HW;

    const uint4* base = px + (size_t)n * PIMG + (size_t)h * PHW + w;
    uint4 xt[NTAP];
    #pragma unroll
    for (int kh = 0; kh < 3; ++kh)
        #pragma unroll
        for (int kw = 0; kw < 3; ++kw)
            xt[kh * 3 + kw] = base[kh * PHW + kw];

    int pt = (h == 0) ? 1 : ((h == HW - 1) ? 2 : 0);
    int pw = (w == 0) ? 1 : ((w == HW - 1) ? 2 : 0);
    int o0 = blockIdx.y * 32;
    const int* cp = scorr + (pt * 3 + pw) * OC + o0;   // LDS, per-lane

    const uint4* wq0 = wpk + (size_t)o0 * NTAP;        // uniform -> scalar loads
    const float* outbase = out + (size_t)(n * OC + o0) * HWSZ;  // uniform

    #pragma unroll
    for (int i = 0; i < 32; ++i) {
        const uint4* wq = wq0 + i * NTAP;
        uint32_t a0 = 0, a1 = 0, a2 = 0, a3 = 0;
        #pragma unroll
        for (int t = 0; t < NTAP; ++t) {
            uint4 wv = wq[t];
            bcnt_acc(a0, xt[t].x ^ wv.x);
            bcnt_acc(a1, xt[t].y ^ wv.y);
            bcnt_acc(a2, xt[t].z ^ wv.z);
            bcnt_acc(a3, xt[t].w ^ wv.w);
        }
        int s = (int)(a0 + a1 + a2 + a3);
        int val = NTAP * C - cp[i] - 2 * s;
        float* opi = const_cast<float*>(outbase) + (size_t)i * HWSZ;  // uniform base
        opi[hw] = (float)val;                                         // saddr + voffset
    }
}

// ---------------------------------------------------------------------------
extern "C" void kernel_launch(void* const* d_in, const int* in_sizes, int n_in,
                              void* d_out, int out_size, void* d_ws, size_t ws_size,
                              hipStream_t stream) {
    const float* x   = (const float*)d_in[0];
    const float* wts = (const float*)d_in[1];
    float* out = (float*)d_out;

    uint8_t* ws = (uint8_t*)d_ws;
    size_t px_bytes   = (size_t)NIMG * PIMG * sizeof(uint4);   // 6,653,952
    size_t wpk_bytes  = (size_t)OC * NTAP * sizeof(uint4);     // 18,432
    size_t popw_bytes = (size_t)OC * NTAP * sizeof(int);       // 4,608
    uint4* px    = (uint4*)ws;
    uint4* wpk   = (uint4*)(ws + px_bytes);
    int*   popcw = (int*)(ws + px_bytes + wpk_bytes);
    int*   corr  = (int*)(ws + px_bytes + wpk_bytes + popw_bytes);

    int nfill = NIMG * PIMG;  // uint4 cells
    hipLaunchKernelGGL(fill_zero_u4, dim3((nfill + 255) / 256), dim3(256), 0, stream,
                       px, nfill);
    hipLaunchKernelGGL(pack_weights, dim3((OC * NTAP + 255) / 256), dim3(256), 0, stream,
                       wts, wpk, popcw);
    hipLaunchKernelGGL(mk_corr, dim3((9 * OC + 255) / 256), dim3(256), 0, stream,
                       popcw, corr);
    hipLaunchKernelGGL(pack_x, dim3((NIMG * 4 * (HWSZ / 4) + 255) / 256), dim3(256), 0, stream,
                       x, (uint32_t*)px);
    hipLaunchKernelGGL(bconv, dim3(NIMG * 49, 4), dim3(256), 0, stream,
                       px, wpk, corr, out);
}

// Round 3
// 188.583 us; speedup vs baseline: 1.2846x; 1.0317x over previous
//
#include <hip/hip_runtime.h>
#include <cstdint>
#include <cstddef>

// Problem constants
#define NIMG 32
#define C    128
#define OC   128
#define HW   112
#define HWSZ (HW * HW)      // 12544
#define PHW  114            // padded spatial dim
#define PIMG (PHW * PHW)    // 12996 padded cells per image
#define NTAP 9

// ---------------------------------------------------------------------------
// Zero-fill the padded packed-x buffer (borders must read as 0 bits).
__global__ void fill_zero_u4(uint4* __restrict__ p, int n) {
    int i = blockIdx.x * blockDim.x + threadIdx.x;
    if (i < n) p[i] = make_uint4(0u, 0u, 0u, 0u);
}

// ---------------------------------------------------------------------------
// Pack weights: (O=128, I=128, 3, 3) fp32 -> per (o,tap) 128-bit mask (uint4),
// bit c set iff w[o][c][tap] < 0.  Also store popcount per (o,tap).
__global__ void pack_weights(const float* __restrict__ w,
                             uint4* __restrict__ wpk,
                             int* __restrict__ popcw) {
    int idx = blockIdx.x * blockDim.x + threadIdx.x;   // (o, tap)
    if (idx >= OC * NTAP) return;
    int o = idx / NTAP, tap = idx % NTAP;
    uint32_t m[4] = {0u, 0u, 0u, 0u};
    for (int c = 0; c < C; ++c) {
        uint32_t bit = __float_as_uint(w[(size_t)(o * C + c) * NTAP + tap]) >> 31;
        m[c >> 5] |= bit << (c & 31);
    }
    wpk[idx] = make_uint4(m[0], m[1], m[2], m[3]);
    popcw[idx] = __popc(m[0]) + __popc(m[1]) + __popc(m[2]) + __popc(m[3]);
}

// ---------------------------------------------------------------------------
// Border-base table: base[pat][o] = 9*C - sum over invalid taps of
// (C - 2*popcw[o][tap]), so that out = base - 2*popc_total directly.
// pat = pt*3+pw, pt: 0=interior 1=top(h==0) 2=bottom(h==111);
// pw: 0=interior 1=left(w==0) 2=right(w==111).
__global__ void mk_base(const int* __restrict__ popcw, int* __restrict__ baset) {
    int idx = blockIdx.x * blockDim.x + threadIdx.x;   // pat*128 + o
    if (idx >= 9 * OC) return;
    int pat = idx >> 7, o = idx & 127;
    int pt = pat / 3, pw = pat % 3;
    int inv = 0;
    if (pt == 1) inv |= 0b000000111;
    if (pt == 2) inv |= 0b111000000;
    if (pw == 1) inv |= 0b001001001;
    if (pw == 2) inv |= 0b100100100;
    int s = NTAP * C;
    for (int t = 0; t < NTAP; ++t)
        if ((inv >> t) & 1) s -= C - 2 * popcw[o * NTAP + t];
    baset[idx] = s;
}

// ---------------------------------------------------------------------------
// Pack activations: x (N,C,112,112) fp32 -> padded bit buffer.
// One thread = (n, word-of-32-channels, 2 consecutive w positions).
// 12544 waves for latency hiding on the 50KB-strided channel gather.
__global__ void pack_x(const float* __restrict__ x, uint32_t* __restrict__ pxw) {
    int t = blockIdx.x * blockDim.x + threadIdx.x;
    const int per_img = HWSZ / 2;                      // 6272 (divisible by 64)
    if (t >= NIMG * 4 * per_img) return;
    int p = t % per_img;                               // lane-fastest -> coalesced
    int g = t / per_img;
    int word = g & 3, n = g >> 2;
    int hw0 = p * 2;
    int h = hw0 / HW, w0 = hw0 % HW;                   // 112 % 2 == 0: no row crossing

    uint32_t m0 = 0u, m1 = 0u;
    const float* xp = x + ((size_t)n * C + word * 32) * HWSZ + hw0;
    #pragma unroll
    for (int cc = 0; cc < 32; ++cc) {
        float2 v = *reinterpret_cast<const float2*>(xp + (size_t)cc * HWSZ);
        m0 |= (__float_as_uint(v.x) >> 31) << cc;
        m1 |= (__float_as_uint(v.y) >> 31) << cc;
    }
    uint32_t* dst = pxw + (((size_t)n * PIMG + (size_t)(h + 1) * PHW + (w0 + 1)) << 2) + word;
    dst[0] = m0;
    dst[4] = m1;
}

// ---------------------------------------------------------------------------
__device__ __forceinline__ void bcnt_acc(uint32_t& acc, uint32_t v) {
    // acc = popc(v) + acc, guaranteed single instruction
    asm("v_bcnt_u32_b32 %0, %1, %0" : "+v"(acc) : "v"(v));
}

// Binary conv: out[n][o][h][w] = base[pat][o] - 2*popc(X^W).
// Block = 256 consecutive hw positions of one image; blockIdx.y = 32-wide
// output-channel slab.  Weights + base table staged in LDS: weight reads are
// wave-uniform ds_read_b128 broadcasts on the lgkm pipe (overlaps VALU),
// removing the per-o scalar-load waits that stalled the previous version.
__global__ __launch_bounds__(256) void bconv(const uint4* __restrict__ px,
                                             const uint4* __restrict__ wpk,
                                             const int* __restrict__ baset,
                                             float* __restrict__ out) {
    __shared__ uint4 swt[32 * NTAP];   // this slab's weights, 4.6 KB
    __shared__ int sbase[9 * 32];      // base[pat][i] for this slab, 1.15 KB

    int o0 = blockIdx.y * 32;
    for (int i = threadIdx.x; i < 32 * NTAP; i += 256)
        swt[i] = wpk[(size_t)o0 * NTAP + i];
    for (int i = threadIdx.x; i < 9 * 32; i += 256) {
        int pat = i >> 5, ii = i & 31;
        sbase[i] = baset[pat * OC + o0 + ii];
    }
    __syncthreads();

    int tile = blockIdx.x;                 // 0 .. 32*49-1
    int n = tile / 49;
    int hw = (tile % 49) * 256 + threadIdx.x;
    int h = hw / HW, w = hw % HW;

    const uint4* base = px + (size_t)n * PIMG + (size_t)h * PHW + w;
    uint4 xt[NTAP];
    #pragma unroll
    for (int kh = 0; kh < 3; ++kh)
        #pragma unroll
        for (int kw = 0; kw < 3; ++kw)
            xt[kh * 3 + kw] = base[kh * PHW + kw];

    int pt = (h == 0) ? 1 : ((h == HW - 1) ? 2 : 0);
    int pw = (w == 0) ? 1 : ((w == HW - 1) ? 2 : 0);
    const int* cb = sbase + (pt * 3 + pw) * 32;        // LDS, per-lane

    const float* outbase = out + (size_t)(n * OC + o0) * HWSZ;  // uniform

    #pragma unroll 8
    for (int i = 0; i < 32; ++i) {
        const uint4* wq = swt + i * NTAP;              // LDS, wave-uniform
        uint32_t a0 = 0, a1 = 0, a2 = 0, a3 = 0;
        #pragma unroll
        for (int t = 0; t < NTAP; ++t) {
            uint4 wv = wq[t];
            bcnt_acc(a0, xt[t].x ^ wv.x);
            bcnt_acc(a1, xt[t].y ^ wv.y);
            bcnt_acc(a2, xt[t].z ^ wv.z);
            bcnt_acc(a3, xt[t].w ^ wv.w);
        }
        int s = (int)(a0 + a1 + a2 + a3);
        int val = cb[i] - 2 * s;
        float* opi = const_cast<float*>(outbase) + (size_t)i * HWSZ;  // uniform base
        opi[hw] = (float)val;                                         // saddr + voffset
    }
}

// ---------------------------------------------------------------------------
extern "C" void kernel_launch(void* const* d_in, const int* in_sizes, int n_in,
                              void* d_out, int out_size, void* d_ws, size_t ws_size,
                              hipStream_t stream) {
    const float* x   = (const float*)d_in[0];
    const float* wts = (const float*)d_in[1];
    float* out = (float*)d_out;

    uint8_t* ws = (uint8_t*)d_ws;
    size_t px_bytes   = (size_t)NIMG * PIMG * sizeof(uint4);   // 6,653,952
    size_t wpk_bytes  = (size_t)OC * NTAP * sizeof(uint4);     // 18,432
    size_t popw_bytes = (size_t)OC * NTAP * sizeof(int);       // 4,608
    uint4* px    = (uint4*)ws;
    uint4* wpk   = (uint4*)(ws + px_bytes);
    int*   popcw = (int*)(ws + px_bytes + wpk_bytes);
    int*   baset = (int*)(ws + px_bytes + wpk_bytes + popw_bytes);

    int nfill = NIMG * PIMG;  // uint4 cells
    hipLaunchKernelGGL(fill_zero_u4, dim3((nfill + 255) / 256), dim3(256), 0, stream,
                       px, nfill);
    hipLaunchKernelGGL(pack_weights, dim3((OC * NTAP + 255) / 256), dim3(256), 0, stream,
                       wts, wpk, popcw);
    hipLaunchKernelGGL(mk_base, dim3((9 * OC + 255) / 256), dim3(256), 0, stream,
                       popcw, baset);
    hipLaunchKernelGGL(pack_x, dim3((NIMG * 4 * (HWSZ / 2) + 255) / 256), dim3(256), 0, stream,
                       x, (uint32_t*)px);
    hipLaunchKernelGGL(bconv, dim3(NIMG * 49, 4), dim3(256), 0, stream,
                       px, wpk, baset, out);
}